// Round 8
// baseline (377.225 us; speedup 1.0000x reference)
//
#include <hip/hip_runtime.h>

#define V 255
#define L 16
#define E (V*L)      // 4080
#define P 8
#define CLIPV 10.0f

typedef __attribute__((ext_vector_type(2))) float f32x2;

__device__ __forceinline__ f32x2 splat(float a) { return (f32x2){a, a}; }
__device__ __forceinline__ f32x2 pk_fma(f32x2 a, f32x2 b, f32x2 c) {
    return __builtin_elementwise_fma(a, b, c);
}

// tanh(0.5 * clip(s, -10, 10)) = 1 - 2/(exp(clip(s))+1), per component
__device__ __forceinline__ f32x2 tanh_half_clip_pk(f32x2 s) {
    f32x2 t = __builtin_elementwise_min(
                  __builtin_elementwise_max(s, splat(-CLIPV)), splat(CLIPV));
    f32x2 r;
    float ex = __expf(t.x); r.x = 1.0f - __fdividef(2.0f, ex + 1.0f);
    float ey = __expf(t.y); r.y = 1.0f - __fdividef(2.0f, ey + 1.0f);
    return r;
}

// log((1+r)/(1-r+1e-9) + 1e-9); |r| <= 1 here so no clip needed (identity)
__device__ __forceinline__ float logratio(float r) {
    return __logf(__fdividef(1.0f + r, 1.0f - r + 1e-9f) + 1e-9f);
}

// Transposed layout: flat index i = row*16+col of [V][L] -> element col*V+row.
__device__ __forceinline__ int tr_elem(int i) {
    return (i & (L - 1)) * V + (i >> 4);
}

// thread = (v, q): 4 threads per check-node v; q picks the m/l quad.
// Two (b,p) units packed in f32x2. Ping-pong S0/S1: fixed parity --
// t0 writes S0; even reads S0 writes S1; odd reads S1 writes S0; final reads S1.
// One barrier per phase.
template <int MODE>
__global__ __launch_bounds__(1024, 8) void bpq_kernel(
    const float* __restrict__ x,
    const float* __restrict__ oddw_v,
    const float* __restrict__ oddw_e,
    const float* __restrict__ w_e_out,
    const int*   __restrict__ perma,
    const int*   __restrict__ rc_idx,
    const int*   __restrict__ cr_idx,
    float* __restrict__ eo_ws,     // MODE 0
    const int* __restrict__ invp,  // MODE 1
    float* __restrict__ out)       // MODE 1
{
    __shared__ f32x2 S0[E];   // 32.6 KB
    __shared__ f32x2 S1[E];   // 32.6 KB

    const int tid = threadIdx.x;
    const int v = tid >> 2;            // 0..255 (255 inactive)
    const int q = tid & 3;             // quad: m,l in [4q, 4q+3]
    const int blk = blockIdx.x;        // pair id, 0 .. Bx*P/2-1
    const int b  = blk >> 2;
    const int pA = (blk & 3) * 2;
    const int pB = pA + 1;
    const bool act = (v < V);

    // packed transposed element indices: lo16 = rc (odd/final), hi16 = cr (even)
    unsigned pk[L];
    f32x2 xv = splat(0.0f);
    if (act) {
        const int4* rc4 = (const int4*)(rc_idx + v * L);
        const int4* cr4 = (const int4*)(cr_idx + v * L);
#pragma unroll
        for (int i = 0; i < 4; ++i) {
            int4 a = rc4[i];
            int4 c = cr4[i];
            pk[4*i+0] = (unsigned)tr_elem(a.x) | ((unsigned)tr_elem(c.x) << 16);
            pk[4*i+1] = (unsigned)tr_elem(a.y) | ((unsigned)tr_elem(c.y) << 16);
            pk[4*i+2] = (unsigned)tr_elem(a.z) | ((unsigned)tr_elem(c.z) << 16);
            pk[4*i+3] = (unsigned)tr_elem(a.w) | ((unsigned)tr_elem(c.w) << 16);
        }
        const float* xrow = x + b * (V + 1);
        xv.x = xrow[perma[pA * (V + 1) + v + 1]];
        xv.y = xrow[perma[pB * (V + 1) + v + 1]];
    }

    // ---- t=0 odd layer: message==0 -> rank-1 (write S0) ----
    if (act) {
        float4 wv4 = *(const float4*)(oddw_v + 4 * q);
        S0[(4*q + 0) * V + v] = tanh_half_clip_pk(xv * wv4.x);
        S0[(4*q + 1) * V + v] = tanh_half_clip_pk(xv * wv4.y);
        S0[(4*q + 2) * V + v] = tanh_half_clip_pk(xv * wv4.z);
        S0[(4*q + 3) * V + v] = tanh_half_clip_pk(xv * wv4.w);
    }
    __syncthreads();

#pragma unroll 1
    for (int t = 0; t < 5; ++t) {
        // ===== even layer (read S0, write S1) =====
        // r_l = prod(e)/e_l  (exactly the reference's jnp.prod(e)/e form)
        if (act) {
            f32x2 tp0 = splat(1.0f), tp1 = splat(1.0f);
            f32x2 tp2 = splat(1.0f), tp3 = splat(1.0f);
            f32x2 m0, m1, m2, m3;   // this thread's 4 e-values
#pragma unroll
            for (int l = 0; l < L; ++l) {
                f32x2 qv = S0[pk[l] >> 16];      // 4-lane broadcast read
                qv.x = (qv.x == 0.0f) ? 1.0f : qv.x;
                qv.y = (qv.y == 0.0f) ? 1.0f : qv.y;
                if ((l >> 2) == q) {             // predicated capture, const idx
                    if ((l & 3) == 0) m0 = qv;
                    else if ((l & 3) == 1) m1 = qv;
                    else if ((l & 3) == 2) m2 = qv;
                    else m3 = qv;
                }
                if ((l & 3) == 0) tp0 = tp0 * qv;
                else if ((l & 3) == 1) tp1 = tp1 * qv;
                else if ((l & 3) == 2) tp2 = tp2 * qv;
                else tp3 = tp3 * qv;
            }
            f32x2 total = (tp0 * tp1) * (tp2 * tp3);
            f32x2 o;
            o.x = logratio(__fdividef(total.x, m0.x));
            o.y = logratio(__fdividef(total.y, m0.y));
            S1[(4*q + 0) * V + v] = o;
            o.x = logratio(__fdividef(total.x, m1.x));
            o.y = logratio(__fdividef(total.y, m1.y));
            S1[(4*q + 1) * V + v] = o;
            o.x = logratio(__fdividef(total.x, m2.x));
            o.y = logratio(__fdividef(total.y, m2.y));
            S1[(4*q + 2) * V + v] = o;
            o.x = logratio(__fdividef(total.x, m3.x));
            o.y = logratio(__fdividef(total.y, m3.y));
            S1[(4*q + 3) * V + v] = o;
        }
        __syncthreads();

        // ===== odd layer (round t+1): read S1, write S0 =====
        if (t < 4) {
            const float* __restrict__ wmrow = oddw_e + (t + 1) * (L * L);
            if (act) {
                float4 wv4 = *(const float4*)(oddw_v + (t + 1) * L + 4 * q);
                f32x2 s0 = xv * wv4.x, s1 = xv * wv4.y;
                f32x2 s2 = xv * wv4.z, s3 = xv * wv4.w;
#pragma unroll
                for (int l = 0; l < L; ++l) {
                    f32x2 el = S1[pk[l] & 0xffffu];   // 4-lane broadcast read
                    float4 w4 = *(const float4*)(wmrow + l * L + 4 * q);
                    // diagonal mask: m == l possible only at component l&3
                    // when l>>2 == q -> zero that single weight (1 cndmask)
                    float wa = w4.x, wb = w4.y, wc = w4.z, wd = w4.w;
                    if ((l >> 2) == q) {
                        if ((l & 3) == 0) wa = 0.0f;
                        else if ((l & 3) == 1) wb = 0.0f;
                        else if ((l & 3) == 2) wc = 0.0f;
                        else wd = 0.0f;
                    }
                    s0 = pk_fma(el, splat(wa), s0);
                    s1 = pk_fma(el, splat(wb), s1);
                    s2 = pk_fma(el, splat(wc), s2);
                    s3 = pk_fma(el, splat(wd), s3);
                }
                S0[(4*q + 0) * V + v] = tanh_half_clip_pk(s0);
                S0[(4*q + 1) * V + v] = tanh_half_clip_pk(s1);
                S0[(4*q + 2) * V + v] = tanh_half_clip_pk(s2);
                S0[(4*q + 3) * V + v] = tanh_half_clip_pk(s3);
            }
            __syncthreads();
        }
    }

    // ---- final: gather S1 via rc, dot with w_e_out (uniform s_loads) ----
    if (act) {
        f32x2 d = splat(0.0f);
#pragma unroll
        for (int l = 0; l < L; ++l)
            d = pk_fma(S1[pk[l] & 0xffffu], splat(w_e_out[l]), d);
        if (q == 0) {
            const int uA = blk * 2;
            if (MODE == 0) {
                eo_ws[(size_t)uA * V + v]       = d.x;
                eo_ws[(size_t)(uA + 1) * V + v] = d.y;
            } else {
                int ja = invp[pA * (V + 1) + (v + 1)];
                int jb = invp[pB * (V + 1) + (v + 1)];
                atomicAdd(&out[b * (V + 1) + ja], d.x);
                atomicAdd(&out[b * (V + 1) + jb], d.y);
            }
        }
    }
}

// gather-sum epilogue (MODE 0 path)
__global__ __launch_bounds__(256) void out_kernel(
    const float* __restrict__ x,
    const float* __restrict__ eo_ws,
    const int* __restrict__ perma,
    float* __restrict__ out)
{
    const int b = blockIdx.x;
    const int j = threadIdx.x;   // 0..255
    float acc = x[b * (V + 1) + j];
#pragma unroll
    for (int p = 0; p < P; ++p) {
        int idx = perma[p * (V + 1) + j];
        if (idx > 0) acc += eo_ws[((size_t)(b * P + p)) * V + (idx - 1)];
    }
    out[b * (V + 1) + j] = acc;
}

// fallback helpers (MODE 1 path)
__global__ __launch_bounds__(256) void inv_kernel(const int* __restrict__ perma,
                                                  int* __restrict__ invp)
{
    int p = blockIdx.x, j = threadIdx.x;
    invp[p * (V + 1) + perma[p * (V + 1) + j]] = j;
}

__global__ __launch_bounds__(256) void copy_kernel(const float* __restrict__ x,
                                                   float* __restrict__ out, int n)
{
    int i = blockIdx.x * 256 + threadIdx.x;
    if (i < n) out[i] = x[i];
}

extern "C" void kernel_launch(void* const* d_in, const int* in_sizes, int n_in,
                              void* d_out, int out_size, void* d_ws, size_t ws_size,
                              hipStream_t stream)
{
    const float* x       = (const float*)d_in[0];
    const float* oddw_v  = (const float*)d_in[2];
    const float* oddw_e  = (const float*)d_in[3];
    const float* w_e_out = (const float*)d_in[4];
    const int*   perma   = (const int*)d_in[5];
    const int*   rc      = (const int*)d_in[6];
    const int*   cr      = (const int*)d_in[7];
    float* out = (float*)d_out;

    const int Bx = in_sizes[0] / (V + 1);
    const int nunits = Bx * P;
    const int npairs = nunits / 2;
    const size_t need = (size_t)nunits * V * sizeof(float);

    if (ws_size >= need) {
        float* eo = (float*)d_ws;
        hipLaunchKernelGGL((bpq_kernel<0>), dim3(npairs), dim3(1024), 0, stream,
                           x, oddw_v, oddw_e, w_e_out, perma, rc, cr,
                           eo, (const int*)nullptr, (float*)nullptr);
        hipLaunchKernelGGL(out_kernel, dim3(Bx), dim3(256), 0, stream,
                           x, eo, perma, out);
    } else {
        // atomic fallback: needs P*(V+1)*4 = 8KB workspace for inverse perm
        int* invp = (int*)d_ws;
        hipLaunchKernelGGL(inv_kernel, dim3(P), dim3(V + 1), 0, stream, perma, invp);
        hipLaunchKernelGGL(copy_kernel, dim3((out_size + 255) / 256), dim3(256), 0, stream,
                           x, out, out_size);
        hipLaunchKernelGGL((bpq_kernel<1>), dim3(npairs), dim3(1024), 0, stream,
                           x, oddw_v, oddw_e, w_e_out, perma, rc, cr,
                           (float*)nullptr, invp, out);
    }
}

// Round 9
// 231.696 us; speedup vs baseline: 1.6281x; 1.6281x over previous
//
#include <hip/hip_runtime.h>

#define V 255
#define L 16
#define E (V*L)      // 4080
#define P 8
#define CLIPV 10.0f

typedef __attribute__((ext_vector_type(2))) float f32x2;

__device__ __forceinline__ f32x2 splat(float a) { return (f32x2){a, a}; }
__device__ __forceinline__ f32x2 pk_fma(f32x2 a, f32x2 b, f32x2 c) {
    return __builtin_elementwise_fma(a, b, c);
}

// tanh(0.5 * clip(s, -10, 10)) = 1 - 2/(exp(clip(s))+1), per component
__device__ __forceinline__ f32x2 tanh_half_clip_pk(f32x2 s) {
    f32x2 t = __builtin_elementwise_min(
                  __builtin_elementwise_max(s, splat(-CLIPV)), splat(CLIPV));
    f32x2 r;
    float ex = __expf(t.x); r.x = 1.0f - __fdividef(2.0f, ex + 1.0f);
    float ey = __expf(t.y); r.y = 1.0f - __fdividef(2.0f, ey + 1.0f);
    return r;
}

// zero-substitution (reference: e += (|e|==0))
__device__ __forceinline__ f32x2 zsub(f32x2 o) {
    o.x = (o.x == 0.0f) ? 1.0f : o.x;
    o.y = (o.y == 0.0f) ? 1.0f : o.y;
    return o;
}

// Transposed layout: flat index i = row*16+col of [V][L] -> element col*V+row.
__device__ __forceinline__ int tr_elem(int i) {
    return (i & (L - 1)) * V + (i >> 4);
}

// Fused even+odd using cr(rc(i)) == i: the even-layer value consumed by
// thread v on edge l is logratio(total[row(rc(v,l))] / e_own[v,l]) where
// e_own is the thread's OWN zsub'd odd output. ev never round-trips LDS;
// only e (for the row totals) and the 255-entry totals table do.
// Two (b,p) units per thread packed in f32x2.
template <int MODE>
__global__ __launch_bounds__(256, 4) void bpf_kernel(
    const float* __restrict__ x,
    const float* __restrict__ oddw_v,
    const float* __restrict__ oddw_e,
    const float* __restrict__ w_e_out,
    const int*   __restrict__ perma,
    const int*   __restrict__ rc_idx,
    const int*   __restrict__ cr_idx,
    float* __restrict__ eo_ws,     // MODE 0
    const int* __restrict__ invp,  // MODE 1
    float* __restrict__ out)       // MODE 1
{
    __shared__ f32x2 OO[E];        // zsub'd odd outputs, col-major [l][v]
    __shared__ f32x2 TOT[V + 1];   // per-row products

    const int tid = threadIdx.x;
    const int blk = blockIdx.x;        // pair id
    const int b  = blk >> 2;
    const int pA = (blk & 3) * 2;
    const int pB = pA + 1;
    const int v = tid;
    const bool act = (v < V);

    f32x2 xv = splat(0.0f);
    int crA[L];    // LDS element idx for cr-gather (phase C)
    int rowO[L];   // row((rc(v,l))) for totals read (phase F)
    if (act) {
        const float* xrow = x + b * (V + 1);
        xv.x = xrow[perma[pA * (V + 1) + v + 1]];
        xv.y = xrow[perma[pB * (V + 1) + v + 1]];
#pragma unroll
        for (int l = 0; l < L; ++l) {
            crA[l]  = tr_elem(cr_idx[v * L + l]);
            rowO[l] = rc_idx[v * L + l] >> 4;
        }
    }

    // ---- t=0 odd layer (message==0 -> rank-1), zsub'd into ev ----
    f32x2 ev[L];   // holds e entering even phase, then logratio outputs
    if (act) {
#pragma unroll
        for (int m = 0; m < L; ++m)
            ev[m] = zsub(tanh_half_clip_pk(xv * oddw_v[m]));
    }

#pragma unroll 1
    for (int t = 0; t < 5; ++t) {
        // ---- A: publish e (conflict-free column writes) ----
        if (act) {
#pragma unroll
            for (int m = 0; m < L; ++m) OO[m * V + v] = ev[m];
        }
        __syncthreads();

        // ---- C: cr-gather + tree product -> row total ----
        if (act) {
            f32x2 t0 = splat(1.0f), t1 = splat(1.0f);
            f32x2 t2 = splat(1.0f), t3 = splat(1.0f);
#pragma unroll
            for (int l = 0; l < L; l += 4) {
                t0 = t0 * OO[crA[l + 0]];
                t1 = t1 * OO[crA[l + 1]];
                t2 = t2 * OO[crA[l + 2]];
                t3 = t3 * OO[crA[l + 3]];
            }
            TOT[v] = (t0 * t1) * (t2 * t3);
        }
        __syncthreads();

        // ---- F: totals in, fused logratio; then odd matvec in registers ----
        // r = T/e; log((1+r)/(1-r+1e-9)+1e-9) == log((e+T)/(e-T+1e-9*e))
        // to ~1e-6 (|r| <= tanh(5)^15 ~ 0.9986, so args stay well-positive).
        if (act) {
#pragma unroll
            for (int l = 0; l < L; ++l) {
                f32x2 Tl = TOT[rowO[l]];
                f32x2 e  = ev[l];
                f32x2 num = e + Tl;
                f32x2 den = pk_fma(e, splat(1e-9f), e - Tl);
                f32x2 o;
                o.x = __logf(__fdividef(num.x, den.x));
                o.y = __logf(__fdividef(num.y, den.y));
                ev[l] = o;
            }
            if (t < 4) {
                const float* __restrict__ wv = oddw_v + (t + 1) * L;
                const float* __restrict__ wm = oddw_e + (t + 1) * (L * L);
                f32x2 s[L];
#pragma unroll
                for (int m = 0; m < L; ++m) s[m] = xv * wv[m];  // uniform s_load
#pragma unroll
                for (int l = 0; l < L; ++l) {
                    const f32x2 el = ev[l];
#pragma unroll
                    for (int m = 0; m < L; ++m) {
                        if (m != l)                    // diag mask, compile-time
                            s[m] = pk_fma(el, splat(wm[l * L + m]), s[m]);
                    }
                }
#pragma unroll
                for (int m = 0; m < L; ++m)
                    ev[m] = zsub(tanh_half_clip_pk(s[m]));
            }
        }
    }

    // ---- final: dot with w_e_out straight from registers ----
    if (act) {
        f32x2 d = splat(0.0f);
#pragma unroll
        for (int l = 0; l < L; ++l)
            d = pk_fma(ev[l], splat(w_e_out[l]), d);
        const int uA = blk * 2;
        if (MODE == 0) {
            eo_ws[(size_t)uA * V + v]       = d.x;
            eo_ws[(size_t)(uA + 1) * V + v] = d.y;
        } else {
            int ja = invp[pA * (V + 1) + (v + 1)];
            int jb = invp[pB * (V + 1) + (v + 1)];
            atomicAdd(&out[b * (V + 1) + ja], d.x);
            atomicAdd(&out[b * (V + 1) + jb], d.y);
        }
    }
}

// gather-sum epilogue (MODE 0 path)
__global__ __launch_bounds__(256) void out_kernel(
    const float* __restrict__ x,
    const float* __restrict__ eo_ws,
    const int* __restrict__ perma,
    float* __restrict__ out)
{
    const int b = blockIdx.x;
    const int j = threadIdx.x;   // 0..255
    float acc = x[b * (V + 1) + j];
#pragma unroll
    for (int p = 0; p < P; ++p) {
        int idx = perma[p * (V + 1) + j];
        if (idx > 0) acc += eo_ws[((size_t)(b * P + p)) * V + (idx - 1)];
    }
    out[b * (V + 1) + j] = acc;
}

// fallback helpers (MODE 1 path)
__global__ __launch_bounds__(256) void inv_kernel(const int* __restrict__ perma,
                                                  int* __restrict__ invp)
{
    int p = blockIdx.x, j = threadIdx.x;
    invp[p * (V + 1) + perma[p * (V + 1) + j]] = j;
}

__global__ __launch_bounds__(256) void copy_kernel(const float* __restrict__ x,
                                                   float* __restrict__ out, int n)
{
    int i = blockIdx.x * 256 + threadIdx.x;
    if (i < n) out[i] = x[i];
}

extern "C" void kernel_launch(void* const* d_in, const int* in_sizes, int n_in,
                              void* d_out, int out_size, void* d_ws, size_t ws_size,
                              hipStream_t stream)
{
    const float* x       = (const float*)d_in[0];
    const float* oddw_v  = (const float*)d_in[2];
    const float* oddw_e  = (const float*)d_in[3];
    const float* w_e_out = (const float*)d_in[4];
    const int*   perma   = (const int*)d_in[5];
    const int*   rc      = (const int*)d_in[6];
    const int*   cr      = (const int*)d_in[7];
    float* out = (float*)d_out;

    const int Bx = in_sizes[0] / (V + 1);
    const int nunits = Bx * P;
    const int npairs = nunits / 2;
    const size_t need = (size_t)nunits * V * sizeof(float);

    if (ws_size >= need) {
        float* eo = (float*)d_ws;
        hipLaunchKernelGGL((bpf_kernel<0>), dim3(npairs), dim3(256), 0, stream,
                           x, oddw_v, oddw_e, w_e_out, perma, rc, cr,
                           eo, (const int*)nullptr, (float*)nullptr);
        hipLaunchKernelGGL(out_kernel, dim3(Bx), dim3(256), 0, stream,
                           x, eo, perma, out);
    } else {
        // atomic fallback: needs P*(V+1)*4 = 8KB workspace for inverse perm
        int* invp = (int*)d_ws;
        hipLaunchKernelGGL(inv_kernel, dim3(P), dim3(V + 1), 0, stream, perma, invp);
        hipLaunchKernelGGL(copy_kernel, dim3((out_size + 255) / 256), dim3(256), 0, stream,
                           x, out, out_size);
        hipLaunchKernelGGL((bpf_kernel<1>), dim3(npairs), dim3(256), 0, stream,
                           x, oddw_v, oddw_e, w_e_out, perma, rc, cr,
                           (float*)nullptr, invp, out);
    }
}